// Round 1
// baseline (281.740 us; speedup 1.0000x reference)
//
#include <hip/hip_runtime.h>
#include <math.h>

#define B_BAGS 8
#define N_INST 8192
#define D_DIM  512
#define H_ATT  64
#define TOPK_K 2457
#define ROWS_TOTAL (B_BAGS * N_INST)

typedef __attribute__((ext_vector_type(8))) short bf16x8;
typedef __attribute__((ext_vector_type(4))) float f32x4;
typedef __attribute__((ext_vector_type(4))) unsigned short u16x4;

// ---- workspace layout (bytes) ----
#define WS_W1T_HI 0                         // [64][512] bf16 bits
#define WS_W1T_LO 65536                     // [64][512] bf16 bits
#define WS_META   131072                    // 8 x uint Tbits, 8 x int Icut
#define WS_PART3  131584                    // [8][32][512] f32 gather partials
#define WS_PART1  (WS_PART3 + 8*32*512*4)   // [8][8][512] f32 layer1 partials
#define WS_PART2  (WS_PART1 + 8*8*512*4)    // [8][8][512] f32 layer2 partials
// total ~918 KB

__device__ __forceinline__ unsigned short bf16_rn(float f) {
  unsigned int x = __float_as_uint(f);
  unsigned int r = (x + 0x7FFFu + ((x >> 16) & 1u)) >> 16;
  return (unsigned short)r;
}
__device__ __forceinline__ float bf16_f(unsigned short u) {
  return __uint_as_float(((unsigned int)u) << 16);
}
__device__ __forceinline__ float gelu_f(float v) {
  // jax.nn.gelu default: tanh approximation
  float u = 0.7978845608028654f * (v + 0.044715f * v * v * v);
  return 0.5f * v * (1.0f + tanhf(u));
}

// ---------------- kernel 0: transpose + hi/lo split of aW1 -> ws ----------------
__global__ __launch_bounds__(256) void k_prep(const float* __restrict__ aW1,
                                              unsigned short* __restrict__ hi,
                                              unsigned short* __restrict__ lo) {
  int o = blockIdx.x * 256 + threadIdx.x;   // over 64*512 outputs, layout [n][k]
  if (o >= H_ATT * D_DIM) return;
  int n = o >> 9;
  int k = o & 511;
  float v = aW1[k * H_ATT + n];
  unsigned short h = bf16_rn(v);
  unsigned short l = bf16_rn(v - bf16_f(h));
  hi[o] = h;
  lo[o] = l;
}

// ---------------- kernel 1: fused score MLP -> sigmoid weights ----------------
#define BM 128
#define BK 64
#define LDK 72   // padded LDS k-stride (bf16 elems) to break bank conflicts

__global__ __launch_bounds__(256, 2) void k_scores(
    const float* __restrict__ x,
    const unsigned short* __restrict__ w1t_hi,
    const unsigned short* __restrict__ w1t_lo,
    const float* __restrict__ ab1, const float* __restrict__ aW2,
    const float* __restrict__ ab2, float* __restrict__ wout) {
  __shared__ unsigned short A_hi[BM * LDK];
  __shared__ unsigned short A_lo[BM * LDK];
  __shared__ unsigned short Bh[H_ATT * LDK];
  __shared__ unsigned short Bl[H_ATT * LDK];

  int tid = threadIdx.x;
  int wave = tid >> 6, lane = tid & 63;
  int rowBase = blockIdx.x * BM;

  f32x4 acc[2][4];
#pragma unroll
  for (int s = 0; s < 2; s++)
#pragma unroll
    for (int t = 0; t < 4; t++) acc[s][t] = (f32x4){0.f, 0.f, 0.f, 0.f};

  for (int kc = 0; kc < D_DIM; kc += BK) {
    // stage X tile: 128 rows x 64 k (fp32) -> bf16 hi/lo in LDS
#pragma unroll
    for (int i = 0; i < 8; i++) {
      int idx = tid + i * 256;            // 0..2047 float4s
      int r = idx >> 4;                   // row 0..127
      int kk = (idx & 15) << 2;           // 0..60
      const float4 v = *reinterpret_cast<const float4*>(
          x + (size_t)(rowBase + r) * D_DIM + kc + kk);
      unsigned short h0 = bf16_rn(v.x), h1 = bf16_rn(v.y), h2 = bf16_rn(v.z), h3 = bf16_rn(v.w);
      unsigned short l0 = bf16_rn(v.x - bf16_f(h0));
      unsigned short l1 = bf16_rn(v.y - bf16_f(h1));
      unsigned short l2 = bf16_rn(v.z - bf16_f(h2));
      unsigned short l3 = bf16_rn(v.w - bf16_f(h3));
      int a = r * LDK + kk;
      *reinterpret_cast<u16x4*>(&A_hi[a]) = (u16x4){h0, h1, h2, h3};
      *reinterpret_cast<u16x4*>(&A_lo[a]) = (u16x4){l0, l1, l2, l3};
    }
    // stage W chunk (already transposed [n][k] bf16 in ws)
#pragma unroll
    for (int i = 0; i < 2; i++) {
      int idx = tid + i * 256;            // 0..511 groups of 8 bf16
      int n = idx >> 3;
      int kk = (idx & 7) << 3;
      *reinterpret_cast<int4*>(&Bh[n * LDK + kk]) =
          *reinterpret_cast<const int4*>(w1t_hi + n * D_DIM + kc + kk);
      *reinterpret_cast<int4*>(&Bl[n * LDK + kk]) =
          *reinterpret_cast<const int4*>(w1t_lo + n * D_DIM + kc + kk);
    }
    __syncthreads();

#pragma unroll
    for (int k2 = 0; k2 < 2; k2++) {
      int ko = k2 * 32 + (lane >> 4) * 8;
      bf16x8 afh[2], afl[2], bfh[4], bfl[4];
#pragma unroll
      for (int s = 0; s < 2; s++) {
        int r = wave * 32 + s * 16 + (lane & 15);
        afh[s] = *reinterpret_cast<const bf16x8*>(&A_hi[r * LDK + ko]);
        afl[s] = *reinterpret_cast<const bf16x8*>(&A_lo[r * LDK + ko]);
      }
#pragma unroll
      for (int t = 0; t < 4; t++) {
        int n = t * 16 + (lane & 15);
        bfh[t] = *reinterpret_cast<const bf16x8*>(&Bh[n * LDK + ko]);
        bfl[t] = *reinterpret_cast<const bf16x8*>(&Bl[n * LDK + ko]);
      }
#pragma unroll
      for (int s = 0; s < 2; s++)
#pragma unroll
        for (int t = 0; t < 4; t++) {
          acc[s][t] = __builtin_amdgcn_mfma_f32_16x16x32_bf16(afl[s], bfh[t], acc[s][t], 0, 0, 0);
          acc[s][t] = __builtin_amdgcn_mfma_f32_16x16x32_bf16(afh[s], bfl[t], acc[s][t], 0, 0, 0);
          acc[s][t] = __builtin_amdgcn_mfma_f32_16x16x32_bf16(afh[s], bfh[t], acc[s][t], 0, 0, 0);
        }
    }
    __syncthreads();
  }

  // epilogue: h = gelu(acc + ab1); score = h @ aW2 + ab2; w = sigmoid(score)
  int c0 = lane & 15, quad = lane >> 4;
  float w2v[4], b1v[4];
#pragma unroll
  for (int t = 0; t < 4; t++) {
    w2v[t] = aW2[t * 16 + c0];
    b1v[t] = ab1[t * 16 + c0];
  }
  float bias2 = ab2[0];
#pragma unroll
  for (int s = 0; s < 2; s++) {
    float p[4] = {0.f, 0.f, 0.f, 0.f};
#pragma unroll
    for (int t = 0; t < 4; t++)
#pragma unroll
      for (int r = 0; r < 4; r++) {
        float h = gelu_f(acc[s][t][r] + b1v[t]);
        p[r] += h * w2v[t];
      }
#pragma unroll
    for (int off = 1; off < 16; off <<= 1)
#pragma unroll
      for (int r = 0; r < 4; r++) p[r] += __shfl_xor(p[r], off, 64);
    if (c0 == 0) {
      int row = rowBase + wave * 32 + s * 16 + quad * 4;
#pragma unroll
      for (int r = 0; r < 4; r++) {
        float sc = p[r] + bias2;
        wout[row + r] = 1.0f / (1.0f + expf(-sc));
      }
    }
  }
}

// ---------------- kernel 2: exact top-k threshold per bag ----------------
__global__ __launch_bounds__(256) void k_topk(const float* __restrict__ wout,
                                              unsigned int* __restrict__ meta) {
  int b = blockIdx.x;
  const float* w = wout + b * N_INST;
  int tid = threadIdx.x;
  unsigned int v[32];
#pragma unroll
  for (int j = 0; j < 32; j++) v[j] = __float_as_uint(w[j * 256 + tid]);

  __shared__ int red[4];
  __shared__ int bc;
  int lane = tid & 63, wv = tid >> 6;

  // find largest T with count(bits >= T) >= K  (all weights positive -> bits monotone)
  unsigned int lo = 0u, hi = 0x3F800001u;
  while (hi - lo > 1u) {
    unsigned int mid = lo + ((hi - lo) >> 1);
    int c = 0;
#pragma unroll
    for (int j = 0; j < 32; j++) c += (v[j] >= mid) ? 1 : 0;
#pragma unroll
    for (int off = 32; off > 0; off >>= 1) c += __shfl_down(c, off, 64);
    if (lane == 0) red[wv] = c;
    __syncthreads();
    if (tid == 0) bc = red[0] + red[1] + red[2] + red[3];
    __syncthreads();
    if (bc >= TOPK_K) lo = mid; else hi = mid;
  }
  unsigned int T = lo;

  // c1 = count(> T)
  {
    int c = 0;
#pragma unroll
    for (int j = 0; j < 32; j++) c += (v[j] > T) ? 1 : 0;
#pragma unroll
    for (int off = 32; off > 0; off >>= 1) c += __shfl_down(c, off, 64);
    __syncthreads();
    if (lane == 0) red[wv] = c;
    __syncthreads();
    if (tid == 0) bc = red[0] + red[1] + red[2] + red[3];
    __syncthreads();
  }
  int needed = TOPK_K - bc;  // >= 1 always

  // smallest index cutoff m with count(v==T && idx<=m) >= needed (idx = j*256+tid)
  int lom = -1, him = N_INST - 1;
  while (him - lom > 1) {
    int mid = (lom + him) >> 1;
    int c = 0;
#pragma unroll
    for (int j = 0; j < 32; j++) c += (v[j] == T && (j * 256 + tid) <= mid) ? 1 : 0;
#pragma unroll
    for (int off = 32; off > 0; off >>= 1) c += __shfl_down(c, off, 64);
    __syncthreads();
    if (lane == 0) red[wv] = c;
    __syncthreads();
    if (tid == 0) bc = red[0] + red[1] + red[2] + red[3];
    __syncthreads();
    if (bc >= needed) him = mid; else lom = mid;
  }
  if (tid == 0) {
    meta[b] = T;
    ((int*)meta)[8 + b] = him;
  }
}

// ---------------- kernel 3: weighted gather partial sums ----------------
__global__ __launch_bounds__(256) void k_gather(const float* __restrict__ x,
                                                const float* __restrict__ wout,
                                                const unsigned int* __restrict__ meta,
                                                float* __restrict__ part3) {
  int b = blockIdx.x >> 5;
  int blk = blockIdx.x & 31;
  unsigned int T = meta[b];
  int Icut = ((const int*)meta)[8 + b];
  int tid = threadIdx.x;
  int r0 = blk * 256;

  __shared__ int idxs[256];
  __shared__ float wgts[256];
  __shared__ int wcnt[4];

  int r = r0 + tid;
  float wvv = wout[b * N_INST + r];
  unsigned int wu = __float_as_uint(wvv);
  bool sel = (wu > T) || (wu == T && r <= Icut);
  unsigned long long m = __ballot(sel);
  int lane = tid & 63, wave = tid >> 6;
  int pos = __popcll(m & ((1ull << lane) - 1ull));
  if (lane == 0) wcnt[wave] = __popcll(m);
  __syncthreads();
  int base = 0;
  for (int i = 0; i < wave; i++) base += wcnt[i];
  int total = wcnt[0] + wcnt[1] + wcnt[2] + wcnt[3];
  if (sel) {
    idxs[base + pos] = r;
    wgts[base + pos] = wvv;
  }
  __syncthreads();

  float2 acc = {0.f, 0.f};
  const float* xb = x + (size_t)b * N_INST * D_DIM;
#pragma unroll 4
  for (int i = 0; i < total; i++) {
    int rr = idxs[i];
    float ww = wgts[i];
    const float2 xv = *reinterpret_cast<const float2*>(xb + (size_t)rr * D_DIM + tid * 2);
    acc.x += ww * xv.x;
    acc.y += ww * xv.y;
  }
  *reinterpret_cast<float2*>(part3 + (size_t)(b * 32 + blk) * D_DIM + tid * 2) = acc;
}

// ---------------- projection MLP, split over d-slices ----------------
__global__ __launch_bounds__(512) void k_proj1(const float* __restrict__ part3,
                                               const float* __restrict__ pW1,
                                               float* __restrict__ part1) {
  int s = blockIdx.x;  // d-slice 0..7
  __shared__ float emb_s[8][64];
  int tid = threadIdx.x;
  int b = tid >> 6, d = tid & 63;
  int dd = s * 64 + d;
  float e = 0.f;
#pragma unroll 8
  for (int j = 0; j < 32; j++) e += part3[(b * 32 + j) * D_DIM + dd];
  emb_s[b][d] = e * (1.0f / TOPK_K);
  __syncthreads();
  float accv[8] = {0.f, 0.f, 0.f, 0.f, 0.f, 0.f, 0.f, 0.f};
  for (int q = 0; q < 64; q++) {
    float wq = pW1[(s * 64 + q) * D_DIM + tid];
#pragma unroll
    for (int bb = 0; bb < 8; bb++) accv[bb] += emb_s[bb][q] * wq;
  }
#pragma unroll
  for (int bb = 0; bb < 8; bb++) part1[(s * 8 + bb) * D_DIM + tid] = accv[bb];
}

__global__ __launch_bounds__(512) void k_proj2(const float* __restrict__ part1,
                                               const float* __restrict__ pb1,
                                               const float* __restrict__ pW2,
                                               float* __restrict__ part2) {
  int s = blockIdx.x;
  __shared__ float h1_s[8][64];
  int tid = threadIdx.x;
  int b = tid >> 6, d = tid & 63;
  int dd = s * 64 + d;
  float hsum = pb1[dd];
#pragma unroll
  for (int j = 0; j < 8; j++) hsum += part1[(j * 8 + b) * D_DIM + dd];
  h1_s[b][d] = gelu_f(hsum);
  __syncthreads();
  float accv[8] = {0.f, 0.f, 0.f, 0.f, 0.f, 0.f, 0.f, 0.f};
  for (int q = 0; q < 64; q++) {
    float wq = pW2[(s * 64 + q) * D_DIM + tid];
#pragma unroll
    for (int bb = 0; bb < 8; bb++) accv[bb] += h1_s[bb][q] * wq;
  }
#pragma unroll
  for (int bb = 0; bb < 8; bb++) part2[(s * 8 + bb) * D_DIM + tid] = accv[bb];
}

__global__ __launch_bounds__(512) void k_proj3(const float* __restrict__ part2,
                                               const float* __restrict__ pb2,
                                               float* __restrict__ out) {
  int b = blockIdx.x;
  int tid = threadIdx.x;
  float sv = pb2[tid];
#pragma unroll
  for (int j = 0; j < 8; j++) sv += part2[(j * 8 + b) * D_DIM + tid];
  out[b * D_DIM + tid] = sv;
}

extern "C" void kernel_launch(void* const* d_in, const int* in_sizes, int n_in,
                              void* d_out, int out_size, void* d_ws, size_t ws_size,
                              hipStream_t stream) {
  (void)in_sizes; (void)n_in; (void)out_size; (void)ws_size;
  const float* x   = (const float*)d_in[0];
  const float* aW1 = (const float*)d_in[1];
  const float* ab1 = (const float*)d_in[2];
  const float* aW2 = (const float*)d_in[3];
  const float* ab2 = (const float*)d_in[4];
  const float* pW1 = (const float*)d_in[5];
  const float* pb1 = (const float*)d_in[6];
  const float* pW2 = (const float*)d_in[7];
  const float* pb2 = (const float*)d_in[8];

  float* out  = (float*)d_out;
  float* wout = out + B_BAGS * D_DIM;  // weights output region [8][8192]

  char* ws = (char*)d_ws;
  unsigned short* w1t_hi = (unsigned short*)(ws + WS_W1T_HI);
  unsigned short* w1t_lo = (unsigned short*)(ws + WS_W1T_LO);
  unsigned int*   meta   = (unsigned int*)(ws + WS_META);
  float* part3 = (float*)(ws + WS_PART3);
  float* part1 = (float*)(ws + WS_PART1);
  float* part2 = (float*)(ws + WS_PART2);

  k_prep<<<dim3((H_ATT * D_DIM + 255) / 256), dim3(256), 0, stream>>>(aW1, w1t_hi, w1t_lo);
  k_scores<<<dim3(ROWS_TOTAL / BM), dim3(256), 0, stream>>>(x, w1t_hi, w1t_lo, ab1, aW2, ab2, wout);
  k_topk<<<dim3(B_BAGS), dim3(256), 0, stream>>>(wout, meta);
  k_gather<<<dim3(B_BAGS * 32), dim3(256), 0, stream>>>(x, wout, meta, part3);
  k_proj1<<<dim3(8), dim3(512), 0, stream>>>(part3, pW1, part1);
  k_proj2<<<dim3(8), dim3(512), 0, stream>>>(part1, pb1, pW2, part2);
  k_proj3<<<dim3(B_BAGS), dim3(512), 0, stream>>>(part2, pb2, out);
}

// Round 2
// 266.547 us; speedup vs baseline: 1.0570x; 1.0570x over previous
//
#include <hip/hip_runtime.h>
#include <math.h>

#define B_BAGS 8
#define N_INST 8192
#define D_DIM  512
#define H_ATT  64
#define TOPK_K 2457
#define ROWS_TOTAL (B_BAGS * N_INST)

typedef __attribute__((ext_vector_type(8))) short bf16x8;
typedef __attribute__((ext_vector_type(4))) float f32x4;
typedef __attribute__((ext_vector_type(4))) unsigned short u16x4;

// ---- workspace layout (bytes) ----
#define WS_W1T_HI 0                          // [64][512] bf16 bits
#define WS_W1T_LO 65536                      // [64][512] bf16 bits
#define WS_META   131072                     // 8 x uint Tbits, 8 x int Icut
#define WS_PART3  131584                     // [8][64][512] f32 gather partials (1 MB)
#define WS_PART1  (WS_PART3 + 8*64*512*4)    // [8kt][8b][512] f32 layer1 partials
#define WS_PART2  (WS_PART1 + 8*8*512*4)     // [8kt][8b][512] f32 layer2 partials

__device__ __forceinline__ unsigned short bf16_rn(float f) {
  unsigned int x = __float_as_uint(f);
  unsigned int r = (x + 0x7FFFu + ((x >> 16) & 1u)) >> 16;
  return (unsigned short)r;
}
__device__ __forceinline__ float bf16_f(unsigned short u) {
  return __uint_as_float(((unsigned int)u) << 16);
}
__device__ __forceinline__ float gelu_f(float v) {
  float u = 0.7978845608028654f * (v + 0.044715f * v * v * v);
  return 0.5f * v * (1.0f + tanhf(u));
}

// ---------------- kernel 0: transpose + hi/lo split of aW1 -> ws ----------------
__global__ __launch_bounds__(256) void k_prep(const float* __restrict__ aW1,
                                              unsigned short* __restrict__ hi,
                                              unsigned short* __restrict__ lo) {
  int o = blockIdx.x * 256 + threadIdx.x;   // over 64*512 outputs, layout [n][k]
  if (o >= H_ATT * D_DIM) return;
  int n = o >> 9;
  int k = o & 511;
  float v = aW1[k * H_ATT + n];
  unsigned short h = bf16_rn(v);
  unsigned short l = bf16_rn(v - bf16_f(h));
  hi[o] = h;
  lo[o] = l;
}

// ---------------- kernel 1: fused score MLP -> sigmoid weights ----------------
#define BM 128
#define BK 64
#define LDK 72   // padded LDS k-stride (bf16 elems)

__global__ __launch_bounds__(256, 2) void k_scores(
    const float* __restrict__ x,
    const unsigned short* __restrict__ w1t_hi,
    const unsigned short* __restrict__ w1t_lo,
    const float* __restrict__ ab1, const float* __restrict__ aW2,
    const float* __restrict__ ab2, float* __restrict__ wout) {
  __shared__ unsigned short A_hi[BM * LDK];
  __shared__ unsigned short A_lo[BM * LDK];
  __shared__ unsigned short Bh[H_ATT * LDK];
  __shared__ unsigned short Bl[H_ATT * LDK];

  int tid = threadIdx.x;
  int wave = tid >> 6, lane = tid & 63;
  int rowBase = blockIdx.x * BM;

  f32x4 acc[2][4];
#pragma unroll
  for (int s = 0; s < 2; s++)
#pragma unroll
    for (int t = 0; t < 4; t++) acc[s][t] = (f32x4){0.f, 0.f, 0.f, 0.f};

  float4 xa[8];
  int4 wbh[2], wbl[2];

  auto issue = [&](int kc) {
#pragma unroll
    for (int i = 0; i < 8; i++) {
      int r = (tid >> 4) + i * 16;
      int kk = (tid & 15) << 2;
      xa[i] = *reinterpret_cast<const float4*>(
          x + (size_t)(rowBase + r) * D_DIM + kc + kk);
    }
#pragma unroll
    for (int i = 0; i < 2; i++) {
      int idx = tid + i * 256;
      int n = idx >> 3;
      int kk = (idx & 7) << 3;
      wbh[i] = *reinterpret_cast<const int4*>(w1t_hi + n * D_DIM + kc + kk);
      wbl[i] = *reinterpret_cast<const int4*>(w1t_lo + n * D_DIM + kc + kk);
    }
  };
  auto cvt_store = [&]() {
#pragma unroll
    for (int i = 0; i < 8; i++) {
      const float4 v = xa[i];
      unsigned short h0 = bf16_rn(v.x), h1 = bf16_rn(v.y), h2 = bf16_rn(v.z), h3 = bf16_rn(v.w);
      unsigned short l0 = bf16_rn(v.x - bf16_f(h0));
      unsigned short l1 = bf16_rn(v.y - bf16_f(h1));
      unsigned short l2 = bf16_rn(v.z - bf16_f(h2));
      unsigned short l3 = bf16_rn(v.w - bf16_f(h3));
      int a = ((tid >> 4) + i * 16) * LDK + ((tid & 15) << 2);
      *reinterpret_cast<u16x4*>(&A_hi[a]) = (u16x4){h0, h1, h2, h3};
      *reinterpret_cast<u16x4*>(&A_lo[a]) = (u16x4){l0, l1, l2, l3};
    }
#pragma unroll
    for (int i = 0; i < 2; i++) {
      int idx = tid + i * 256;
      int n = idx >> 3;
      int kk = (idx & 7) << 3;
      *reinterpret_cast<int4*>(&Bh[n * LDK + kk]) = wbh[i];
      *reinterpret_cast<int4*>(&Bl[n * LDK + kk]) = wbl[i];
    }
  };
  auto mfma_phase = [&]() {
#pragma unroll
    for (int k2 = 0; k2 < 2; k2++) {
      int ko = k2 * 32 + (lane >> 4) * 8;
      bf16x8 afh[2], afl[2], bfh[4], bfl[4];
#pragma unroll
      for (int s = 0; s < 2; s++) {
        int r = wave * 32 + s * 16 + (lane & 15);
        afh[s] = *reinterpret_cast<const bf16x8*>(&A_hi[r * LDK + ko]);
        afl[s] = *reinterpret_cast<const bf16x8*>(&A_lo[r * LDK + ko]);
      }
#pragma unroll
      for (int t = 0; t < 4; t++) {
        int n = t * 16 + (lane & 15);
        bfh[t] = *reinterpret_cast<const bf16x8*>(&Bh[n * LDK + ko]);
        bfl[t] = *reinterpret_cast<const bf16x8*>(&Bl[n * LDK + ko]);
      }
#pragma unroll
      for (int s = 0; s < 2; s++)
#pragma unroll
        for (int t = 0; t < 4; t++) {
          acc[s][t] = __builtin_amdgcn_mfma_f32_16x16x32_bf16(afl[s], bfh[t], acc[s][t], 0, 0, 0);
          acc[s][t] = __builtin_amdgcn_mfma_f32_16x16x32_bf16(afh[s], bfl[t], acc[s][t], 0, 0, 0);
          acc[s][t] = __builtin_amdgcn_mfma_f32_16x16x32_bf16(afh[s], bfh[t], acc[s][t], 0, 0, 0);
        }
    }
  };

  issue(0);
  cvt_store();
  __syncthreads();
  for (int kc8 = 0; kc8 < 8; kc8++) {
    if (kc8 < 7) issue((kc8 + 1) * BK);   // loads in flight during MFMA phase
    mfma_phase();
    __syncthreads();
    if (kc8 < 7) {
      cvt_store();
      __syncthreads();
    }
  }

  // epilogue: h = gelu(acc + ab1); score = h @ aW2 + ab2; w = sigmoid(score)
  int c0 = lane & 15, quad = lane >> 4;
  float w2v[4], b1v[4];
#pragma unroll
  for (int t = 0; t < 4; t++) {
    w2v[t] = aW2[t * 16 + c0];
    b1v[t] = ab1[t * 16 + c0];
  }
  float bias2 = ab2[0];
#pragma unroll
  for (int s = 0; s < 2; s++) {
    float p[4] = {0.f, 0.f, 0.f, 0.f};
#pragma unroll
    for (int t = 0; t < 4; t++)
#pragma unroll
      for (int r = 0; r < 4; r++) {
        float h = gelu_f(acc[s][t][r] + b1v[t]);
        p[r] += h * w2v[t];
      }
#pragma unroll
    for (int off = 1; off < 16; off <<= 1)
#pragma unroll
      for (int r = 0; r < 4; r++) p[r] += __shfl_xor(p[r], off, 64);
    if (c0 == 0) {
      int row = rowBase + wave * 32 + s * 16 + quad * 4;
#pragma unroll
      for (int r = 0; r < 4; r++) {
        float sc = p[r] + bias2;
        wout[row + r] = 1.0f / (1.0f + expf(-sc));
      }
    }
  }
}

// ---------------- kernel 2: exact top-k threshold per bag ----------------
__global__ __launch_bounds__(256) void k_topk(const float* __restrict__ wout,
                                              unsigned int* __restrict__ meta) {
  int b = blockIdx.x;
  const float* w = wout + b * N_INST;
  int tid = threadIdx.x;
  unsigned int v[32];
#pragma unroll
  for (int j = 0; j < 32; j++) v[j] = __float_as_uint(w[j * 256 + tid]);

  __shared__ int red[2][4];
  int lane = tid & 63, wv = tid >> 6;
  int pb = 0;

  auto blocksum = [&](int c) -> int {
#pragma unroll
    for (int off = 32; off > 0; off >>= 1) c += __shfl_down(c, off, 64);
    if (lane == 0) red[pb][wv] = c;
    __syncthreads();
    int s = red[pb][0] + red[pb][1] + red[pb][2] + red[pb][3];
    pb ^= 1;
    return s;
  };

  // phase 1: largest T with count(bits >= T) >= K (weights in (0,1) -> bits monotone)
  unsigned int lo = 0u, hi = 0x3F800001u;
  while (hi - lo > 1u) {
    unsigned int mid = lo + ((hi - lo) >> 1);
    int c = 0;
#pragma unroll
    for (int j = 0; j < 32; j++) c += (v[j] >= mid) ? 1 : 0;
    int s = blocksum(c);
    if (s >= TOPK_K) lo = mid; else hi = mid;
  }
  unsigned int T = lo;

  // phase 2: count strictly greater
  int c1;
  {
    int c = 0;
#pragma unroll
    for (int j = 0; j < 32; j++) c += (v[j] > T) ? 1 : 0;
    c1 = blocksum(c);
  }
  int needed = TOPK_K - c1;  // >= 1

  // phase 3: smallest m with count(v==T && idx<=m) >= needed, idx = j*256+tid.
  // O(1) per-thread count via tie bitmask + popcount.
  unsigned int tm = 0;
#pragma unroll
  for (int j = 0; j < 32; j++) tm |= (v[j] == T ? 1u : 0u) << j;
  int lom = -1, him = N_INST - 1;
  while (him - lom > 1) {
    int mid = (lom + him) >> 1;
    unsigned int mask = 0u;
    if (mid >= tid) {
      unsigned int jmax = (unsigned int)(mid - tid) >> 8;   // 0..31
      mask = (2u << jmax) - 1u;
    }
    int s = blocksum((int)__popc(tm & mask));
    if (s >= needed) him = mid; else lom = mid;
  }
  if (tid == 0) {
    meta[b] = T;
    ((int*)meta)[8 + b] = him;
  }
}

// ---------------- kernel 3: weighted gather partial sums ----------------
__global__ __launch_bounds__(256) void k_gather(const float* __restrict__ x,
                                                const float* __restrict__ wout,
                                                const unsigned int* __restrict__ meta,
                                                float* __restrict__ part3) {
  int b = blockIdx.x >> 6;
  int blk = blockIdx.x & 63;
  unsigned int T = meta[b];
  int Icut = ((const int*)meta)[8 + b];
  int tid = threadIdx.x;

  __shared__ int idxs[128];
  __shared__ float wgts[128];
  __shared__ int wcnt[2];

  int r = blk * 128 + tid;
  bool sel = false;
  float wvv = 0.f;
  int pos = 0;
  if (tid < 128) {
    wvv = wout[b * N_INST + r];
    unsigned int wu = __float_as_uint(wvv);
    sel = (wu > T) || (wu == T && r <= Icut);
    unsigned long long m = __ballot(sel);
    int lane = tid & 63;
    pos = __popcll(m & ((1ull << lane) - 1ull));
    if (lane == 0) wcnt[tid >> 6] = __popcll(m);
  }
  __syncthreads();
  int total = wcnt[0] + wcnt[1];
  if (sel) {
    int base = (tid >= 64) ? wcnt[0] : 0;
    idxs[base + pos] = r;
    wgts[base + pos] = wvv;
  }
  __syncthreads();

  float2 acc = {0.f, 0.f};
  const float* xb = x + (size_t)b * N_INST * D_DIM;
#pragma unroll 8
  for (int i = 0; i < total; i++) {
    int rr = idxs[i];
    float ww = wgts[i];
    const float2 xv = *reinterpret_cast<const float2*>(xb + (size_t)rr * D_DIM + tid * 2);
    acc.x += ww * xv.x;
    acc.y += ww * xv.y;
  }
  *reinterpret_cast<float2*>(part3 + (size_t)(b * 64 + blk) * D_DIM + tid * 2) = acc;
}

// ---------------- projection MLP: split-K, 64 blocks per layer ----------------
__global__ __launch_bounds__(256) void k_proj1(const float* __restrict__ part3,
                                               const float* __restrict__ pW1,
                                               float* __restrict__ part1) {
  int jt = blockIdx.x & 7, kt = blockIdx.x >> 3;
  __shared__ float emb_s[512];   // [b*64 + d0], d = kt*64 + d0
  int tid = threadIdx.x;
#pragma unroll
  for (int h = 0; h < 2; h++) {
    int vi = tid + h * 256;
    int b = vi >> 6, d0 = vi & 63;
    const float* p = part3 + (size_t)b * 64 * 512 + kt * 64 + d0;
    float e = 0.f;
#pragma unroll 8
    for (int j = 0; j < 64; j++) e += p[j * 512];
    emb_s[vi] = e * (1.0f / TOPK_K);
  }
  __syncthreads();
  int col = tid & 63, bg = tid >> 6;   // bags bg*2, bg*2+1
  float a0 = 0.f, a1 = 0.f;
  const float* wrow = pW1 + (size_t)(kt * 64) * 512 + jt * 64 + col;
#pragma unroll 8
  for (int q = 0; q < 64; q++) {
    float wq = wrow[q * 512];
    a0 += emb_s[(bg * 2) * 64 + q] * wq;
    a1 += emb_s[(bg * 2 + 1) * 64 + q] * wq;
  }
  part1[kt * 4096 + (bg * 2) * 512 + jt * 64 + col] = a0;
  part1[kt * 4096 + (bg * 2 + 1) * 512 + jt * 64 + col] = a1;
}

__global__ __launch_bounds__(256) void k_proj2(const float* __restrict__ part1,
                                               const float* __restrict__ pb1,
                                               const float* __restrict__ pW2,
                                               float* __restrict__ part2) {
  int jt = blockIdx.x & 7, kt = blockIdx.x >> 3;
  __shared__ float h_s[512];   // [b*64 + j0], j = kt*64 + j0
  int tid = threadIdx.x;
#pragma unroll
  for (int h = 0; h < 2; h++) {
    int vi = tid + h * 256;
    int b = vi >> 6, j0 = vi & 63;
    int jj = kt * 64 + j0;
    float s = pb1[jj];
#pragma unroll
    for (int p = 0; p < 8; p++) s += part1[p * 4096 + b * 512 + jj];
    h_s[vi] = gelu_f(s);
  }
  __syncthreads();
  int col = tid & 63, bg = tid >> 6;
  float a0 = 0.f, a1 = 0.f;
  const float* wrow = pW2 + (size_t)(kt * 64) * 512 + jt * 64 + col;
#pragma unroll 8
  for (int q = 0; q < 64; q++) {
    float wq = wrow[q * 512];
    a0 += h_s[(bg * 2) * 64 + q] * wq;
    a1 += h_s[(bg * 2 + 1) * 64 + q] * wq;
  }
  part2[kt * 4096 + (bg * 2) * 512 + jt * 64 + col] = a0;
  part2[kt * 4096 + (bg * 2 + 1) * 512 + jt * 64 + col] = a1;
}

__global__ __launch_bounds__(512) void k_proj3(const float* __restrict__ part2,
                                               const float* __restrict__ pb2,
                                               float* __restrict__ out) {
  int o = blockIdx.x * 512 + threadIdx.x;   // o = b*512 + j
  int bj = o & 511;
  float s = pb2[bj];
#pragma unroll
  for (int p = 0; p < 8; p++) s += part2[p * 4096 + o];
  out[o] = s;
}

extern "C" void kernel_launch(void* const* d_in, const int* in_sizes, int n_in,
                              void* d_out, int out_size, void* d_ws, size_t ws_size,
                              hipStream_t stream) {
  (void)in_sizes; (void)n_in; (void)out_size; (void)ws_size;
  const float* x   = (const float*)d_in[0];
  const float* aW1 = (const float*)d_in[1];
  const float* ab1 = (const float*)d_in[2];
  const float* aW2 = (const float*)d_in[3];
  const float* ab2 = (const float*)d_in[4];
  const float* pW1 = (const float*)d_in[5];
  const float* pb1 = (const float*)d_in[6];
  const float* pW2 = (const float*)d_in[7];
  const float* pb2 = (const float*)d_in[8];

  float* out  = (float*)d_out;
  float* wout = out + B_BAGS * D_DIM;  // weights output region [8][8192]

  char* ws = (char*)d_ws;
  unsigned short* w1t_hi = (unsigned short*)(ws + WS_W1T_HI);
  unsigned short* w1t_lo = (unsigned short*)(ws + WS_W1T_LO);
  unsigned int*   meta   = (unsigned int*)(ws + WS_META);
  float* part3 = (float*)(ws + WS_PART3);
  float* part1 = (float*)(ws + WS_PART1);
  float* part2 = (float*)(ws + WS_PART2);

  k_prep<<<dim3((H_ATT * D_DIM + 255) / 256), dim3(256), 0, stream>>>(aW1, w1t_hi, w1t_lo);
  k_scores<<<dim3(ROWS_TOTAL / BM), dim3(256), 0, stream>>>(x, w1t_hi, w1t_lo, ab1, aW2, ab2, wout);
  k_topk<<<dim3(B_BAGS), dim3(256), 0, stream>>>(wout, meta);
  k_gather<<<dim3(B_BAGS * 64), dim3(256), 0, stream>>>(x, wout, meta, part3);
  k_proj1<<<dim3(64), dim3(256), 0, stream>>>(part3, pW1, part1);
  k_proj2<<<dim3(64), dim3(256), 0, stream>>>(part1, pb1, pW2, part2);
  k_proj3<<<dim3(B_BAGS), dim3(512), 0, stream>>>(part2, pb2, out);
}